// Round 6
// baseline (494.939 us; speedup 1.0000x reference)
//
#include <hip/hip_runtime.h>
#include <cstdint>
#include <cstddef>

typedef _Float16 f16;
typedef _Float16 half8 __attribute__((ext_vector_type(8)));
typedef _Float16 half4v __attribute__((ext_vector_type(4)));
typedef float floatx4 __attribute__((ext_vector_type(4)));
typedef float floatx16 __attribute__((ext_vector_type(16)));

__device__ __forceinline__ floatx4 mfma16(half8 a, half8 b, floatx4 c) {
    return __builtin_amdgcn_mfma_f32_16x16x32_f16(a, b, c, 0, 0, 0);
}
__device__ __forceinline__ floatx16 mfma32(half8 a, half8 b, floatx16 c) {
    return __builtin_amdgcn_mfma_f32_32x32x16_f16(a, b, c, 0, 0, 0);
}

// async global->LDS, 16B per lane; LDS dest is wave-uniform base + lane*16.
__device__ __forceinline__ void async16(const f16* g, f16* l) {
    __builtin_amdgcn_global_load_lds(
        (const __attribute__((address_space(1))) unsigned int*)(uintptr_t)g,
        (__attribute__((address_space(3))) unsigned int*)(uintptr_t)l,
        16, 0, 0);
}

// ---------------- LayerNorm (fp32 in -> f16 out), one block per row of 1024 ----
__global__ __launch_bounds__(256)
void ln_f16_kernel(const float* __restrict__ x, const float* __restrict__ g,
                   const float* __restrict__ be, f16* __restrict__ y)
{
    int row = blockIdx.x, t = threadIdx.x;
    const float* xr = x + (size_t)row * 1024;
    float4 v = *(const float4*)(xr + t * 4);
    float s1 = v.x + v.y + v.z + v.w;
    float s2 = v.x * v.x + v.y * v.y + v.z * v.z + v.w * v.w;
    #pragma unroll
    for (int off = 32; off >= 1; off >>= 1) {
        s1 += __shfl_xor(s1, off);
        s2 += __shfl_xor(s2, off);
    }
    __shared__ float r1[4], r2[4];
    if ((t & 63) == 0) { r1[t >> 6] = s1; r2[t >> 6] = s2; }
    __syncthreads();
    s1 = r1[0] + r1[1] + r1[2] + r1[3];
    s2 = r2[0] + r2[1] + r2[2] + r2[3];
    float mean = s1 * 0.0009765625f;
    float var  = s2 * 0.0009765625f - mean * mean;
    float rs = rsqrtf(var + 1e-6f);
    float4 gv = *(const float4*)(g + t * 4);
    float4 bv = *(const float4*)(be + t * 4);
    half4v o;
    o[0] = (f16)((v.x - mean) * rs * gv.x + bv.x);
    o[1] = (f16)((v.y - mean) * rs * gv.y + bv.y);
    o[2] = (f16)((v.z - mean) * rs * gv.z + bv.z);
    o[3] = (f16)((v.w - mean) * rs * gv.w + bv.w);
    *(half4v*)(y + (size_t)row * 1024 + t * 4) = o;
}

// ---------------- fp32 [R,C] -> f16 transpose [C,R] --------------------------
__global__ __launch_bounds__(256)
void transpose_f16_kernel(const float* __restrict__ W, f16* __restrict__ WT,
                          int R, int C)
{
    __shared__ float tile[32][33];
    int tx = threadIdx.x & 31, ty0 = threadIdx.x >> 5;
    int r0 = blockIdx.y * 32, c0 = blockIdx.x * 32;
    #pragma unroll
    for (int i = 0; i < 4; ++i)
        tile[ty0 + i * 8][tx] = W[(size_t)(r0 + ty0 + i * 8) * C + c0 + tx];
    __syncthreads();
    #pragma unroll
    for (int i = 0; i < 4; ++i)
        WT[(size_t)(c0 + ty0 + i * 8) * R + r0 + tx] = (f16)tile[tx][ty0 + i * 8];
}

// ---------------- GEMM small-N: C[M,N] = A * BT^T + bias; fp32 out += res ----
// 128x128 tile, BK=64, XOR-swizzled LDS. Double-buffered 2-phase pipeline:
// staging for tile t+1 is ISSUED before computing tile t; the single
// __syncthreads() per K-tile (vmcnt(0)+lgkmcnt(0) drain + barrier) then waits
// only the residual latency not covered by compute.  [R4 WINNER - DO NOT TOUCH]
__global__ __launch_bounds__(256, 2)
void gemm_kernel(const f16* __restrict__ A, const f16* __restrict__ BT,
                 const float* __restrict__ bias, const float* __restrict__ res,
                 float* __restrict__ Cf32, int M, int N, int K)
{
    __shared__ __align__(16) f16 As[2][128 * 64];
    __shared__ __align__(16) f16 Bs[2][128 * 64];
    int m0 = blockIdx.x * 128, n0 = blockIdx.y * 128;
    int t = threadIdx.x, lane = t & 63, wave = t >> 6;
    int quad = lane >> 4, l16 = lane & 15;
    int wm = (wave & 1) * 64, wn = (wave >> 1) * 64;
    int sw = l16 & 7;
    floatx4 acc[4][4] = {};

    // Per-thread staging sources (pre-swizzled) + wave-uniform LDS slots.
    const f16* gA[4]; const f16* gB[4]; int oS[4];
    #pragma unroll
    for (int c = 0; c < 4; ++c) {
        int s = c * 256 + t;
        int row = s >> 3, lg = (s & 7) ^ (row & 7);
        gA[c] = A  + (size_t)(m0 + row) * K + lg * 8;
        gB[c] = BT + (size_t)(n0 + row) * K + lg * 8;
        oS[c] = (c * 256 + (t & ~63)) * 8;
    }

    // Prologue: stage tile 0 into buffer 0.
    #pragma unroll
    for (int c = 0; c < 4; ++c) {
        async16(gA[c], As[0] + oS[c]);
        async16(gB[c], Bs[0] + oS[c]);
    }
    __syncthreads();                       // vmcnt(0) drain + barrier

    int buf = 0;
    for (int k0 = 0; k0 < K; k0 += 64) {
        int kn = k0 + 64;
        if (kn < K) {                      // issue NEXT tile's staging first
            #pragma unroll
            for (int c = 0; c < 4; ++c) {
                async16(gA[c] + kn, As[buf ^ 1] + oS[c]);
                async16(gB[c] + kn, Bs[buf ^ 1] + oS[c]);
            }
        }
        // Compute current tile (resident in As[buf]/Bs[buf]).
        #pragma unroll
        for (int ks = 0; ks < 2; ++ks) {
            int ca = (ks * 4 + quad) ^ sw;
            half8 a[4], b[4];
            #pragma unroll
            for (int i = 0; i < 4; ++i) {
                a[i] = *(const half8*)(As[buf] + (wm + i * 16 + l16) * 64 + ca * 8);
                b[i] = *(const half8*)(Bs[buf] + (wn + i * 16 + l16) * 64 + ca * 8);
            }
            #pragma unroll
            for (int i = 0; i < 4; ++i)
                #pragma unroll
                for (int j = 0; j < 4; ++j)
                    acc[i][j] = mfma16(a[i], b[j], acc[i][j]);
        }
        __syncthreads();                   // waits next tile's loads + barrier
        buf ^= 1;
    }

    #pragma unroll
    for (int j = 0; j < 4; ++j) {
        int col = n0 + wn + j * 16 + l16;
        float bv = bias[col];
        #pragma unroll
        for (int i = 0; i < 4; ++i) {
            int rowb = m0 + wm + i * 16 + quad * 4;
            #pragma unroll
            for (int r = 0; r < 4; ++r) {
                float v = acc[i][j][r] + bv;
                size_t idx = (size_t)(rowb + r) * N + col;
                Cf32[idx] = v + res[idx];
            }
        }
    }
}

// ---------------- GEMM big-tile: 256x128, BK=32, 32x32x16 MFMA ---------------
// 4 waves, each 64x128 (2x4 frags). R4-proven 2-phase prefetch pipeline with
// BK=32 so the double buffer fits 48 KB -> 2 blocks/CU (2 waves/SIMD; the R5
// regression was 1 wave/SIMD). Swizzle upgraded to s2(row)=(row^row>>2^row>>4)&3
// so strided lane groups decorrelate: kills the constant 6.29M 4-way conflicts.
// MODE 1: f16 out + ReLU.  MODE 2: QKV scatter (Q,K->[b,h,s,d]; V->[b,h,d,s]).
template<int MODE>
__global__ __launch_bounds__(256, 2)
void gemm_big_kernel(const f16* __restrict__ A, const f16* __restrict__ BT,
                     const float* __restrict__ bias, f16* __restrict__ Cf16,
                     f16* __restrict__ qb, f16* __restrict__ kb, f16* __restrict__ vb,
                     int M, int N, int K)
{
    __shared__ __align__(16) f16 As[2][256 * 32];   // 16 KB each
    __shared__ __align__(16) f16 Bs[2][128 * 32];   //  8 KB each
    int m0 = blockIdx.x * 256, n0 = blockIdx.y * 128;
    int t = threadIdx.x, lane = t & 63, wave = t >> 6;
    int l32 = lane & 31, kg = lane >> 5;             // k-group (0/1)
    int swz = (l32 ^ (l32 >> 2) ^ (l32 >> 4)) & 3;   // s2(l32)
    floatx16 acc[2][4];
    #pragma unroll
    for (int mi = 0; mi < 2; ++mi)
        #pragma unroll
        for (int jn = 0; jn < 4; ++jn)
            #pragma unroll
            for (int r = 0; r < 16; ++r) acc[mi][jn][r] = 0.f;

    // Per-thread staging sources (pre-swizzled with s2) + wave-uniform slots.
    // A: 256 rows x 32 f16 = 1024 16B-slots (4/thread); B: 512 slots (2/thread).
    const f16* gA[4]; int oA[4];
    #pragma unroll
    for (int c = 0; c < 4; ++c) {
        int s = c * 256 + t;
        int row = s >> 2, phys = s & 3;
        int lg = phys ^ ((row ^ (row >> 2) ^ (row >> 4)) & 3);
        gA[c] = A + (size_t)(m0 + row) * K + lg * 8;
        oA[c] = (c * 256 + (t & ~63)) * 8;
    }
    const f16* gB[2]; int oB[2];
    #pragma unroll
    for (int c = 0; c < 2; ++c) {
        int s = c * 256 + t;
        int row = s >> 2, phys = s & 3;
        int lg = phys ^ ((row ^ (row >> 2) ^ (row >> 4)) & 3);
        gB[c] = BT + (size_t)(n0 + row) * K + lg * 8;
        oB[c] = (c * 256 + (t & ~63)) * 8;
    }

    // Prologue: stage tile 0 into buffer 0.
    #pragma unroll
    for (int c = 0; c < 4; ++c) async16(gA[c], As[0] + oA[c]);
    #pragma unroll
    for (int c = 0; c < 2; ++c) async16(gB[c], Bs[0] + oB[c]);
    __syncthreads();                       // vmcnt(0) drain + barrier

    int buf = 0;
    for (int k0 = 0; k0 < K; k0 += 32) {
        int kn = k0 + 32;
        if (kn < K) {                      // issue NEXT tile's staging first
            #pragma unroll
            for (int c = 0; c < 4; ++c) async16(gA[c] + kn, As[buf ^ 1] + oA[c]);
            #pragma unroll
            for (int c = 0; c < 2; ++c) async16(gB[c] + kn, Bs[buf ^ 1] + oB[c]);
        }
        // Compute current tile: 2 sub-steps of k16.
        #pragma unroll
        for (int ss = 0; ss < 2; ++ss) {
            int cb = ss * 2 + kg;
            half8 a[2], b[4];
            #pragma unroll
            for (int mi = 0; mi < 2; ++mi) {
                int ca = (cb ^ swz ^ (mi * 2));            // +s2 of row-base
                a[mi] = *(const half8*)(As[buf] + (wave * 64 + mi * 32 + l32) * 32 + ca * 8);
            }
            #pragma unroll
            for (int jn = 0; jn < 4; ++jn) {
                int ca = (cb ^ swz ^ ((jn & 1) * 2));
                b[jn] = *(const half8*)(Bs[buf] + (jn * 32 + l32) * 32 + ca * 8);
            }
            #pragma unroll
            for (int mi = 0; mi < 2; ++mi)
                #pragma unroll
                for (int jn = 0; jn < 4; ++jn)
                    acc[mi][jn] = mfma32(a[mi], b[jn], acc[mi][jn]);
        }
        __syncthreads();                   // waits next tile's loads + barrier
        buf ^= 1;
    }

    // C/D layout (32x32): col = lane&31, row = (reg&3) + 8*(reg>>2) + 4*(lane>>5)
    #pragma unroll
    for (int mi = 0; mi < 2; ++mi) {
        int mbase = m0 + wave * 64 + mi * 32 + 4 * kg;
        #pragma unroll
        for (int jn = 0; jn < 4; ++jn) {
            int col = n0 + jn * 32 + l32;
            float bv = bias[col];
            if (MODE == 1) {
                #pragma unroll
                for (int reg = 0; reg < 16; ++reg) {
                    int row = mbase + (reg & 3) + 8 * (reg >> 2);
                    Cf16[(size_t)row * N + col] = (f16)fmaxf(acc[mi][jn][reg] + bv, 0.f);
                }
            } else {
                int part = col >> 10;
                int h = (col >> 6) & 15;
                int d = col & 63;
                if (part == 2) {
                    #pragma unroll
                    for (int rb = 0; rb < 4; ++rb) {
                        int m = mbase + 8 * rb;
                        int bb = m >> 10, s = m & 1023;
                        size_t bh = (size_t)bb * 16 + h;
                        half4v pv;
                        #pragma unroll
                        for (int r = 0; r < 4; ++r) pv[r] = (f16)(acc[mi][jn][rb * 4 + r] + bv);
                        *(half4v*)(vb + (bh * 64 + d) * 1024 + s) = pv;
                    }
                } else {
                    f16* dst0 = part == 0 ? qb : kb;
                    #pragma unroll
                    for (int reg = 0; reg < 16; ++reg) {
                        int m = mbase + (reg & 3) + 8 * (reg >> 2);
                        int bb = m >> 10, s = m & 1023;
                        size_t bh = (size_t)bb * 16 + h;
                        dst0[(bh * 1024 + s) * 64 + d] = (f16)(acc[mi][jn][reg] + bv);
                    }
                }
            }
        }
    }
}

// ---------------- Flash attention v3 ----------------------------------------
__global__ __launch_bounds__(256)
void attn_kernel(const f16* __restrict__ qb, const f16* __restrict__ kb,
                 const f16* __restrict__ vb, const float* __restrict__ mask,
                 f16* __restrict__ ctx)
{
    const int S = 1024;
    int qt = blockIdx.x, h = blockIdx.y, b = blockIdx.z;
    size_t bh = (size_t)b * 16 + h;
    int t = threadIdx.x, lane = t & 63, wv = t >> 6;
    int quad = lane >> 4, l16 = lane & 15;
    int sw = l16 & 7;

    __shared__ __align__(16) f16 Ks[64 * 64];
    __shared__ __align__(16) f16 Vs[64 * 64];
    __shared__ __align__(16) f16 Ps[4][16 * 40];

    int q0 = qt * 64 + wv * 16;
    const f16* qrow = qb + (bh * 1024 + q0 + l16) * 64;
    half8 aq0 = *(const half8*)(qrow + quad * 8);
    half8 aq1 = *(const half8*)(qrow + 32 + quad * 8);

    floatx4 o[4] = {};
    float lsum[4] = {0.f, 0.f, 0.f, 0.f};
    const float scale = 0.125f;
    const float* mrow = mask + b * S;

    for (int kc = 0; kc < S; kc += 64) {
        __syncthreads();
        #pragma unroll
        for (int c = 0; c < 2; ++c) {
            int s = c * 256 + t;
            int row = s >> 3, phys = s & 7;
            int lg = phys ^ (row & 7);
            f16* lk = Ks + (size_t)(c * 256 + (t & ~63)) * 8;
            f16* lv = Vs + (size_t)(c * 256 + (t & ~63)) * 8;
            async16(kb + (bh * 1024 + kc + row) * 64 + lg * 8, lk);
            async16(vb + (bh * 64 + row) * 1024 + kc + lg * 8, lv);
        }
        __syncthreads();

        floatx4 sf[4];
        #pragma unroll
        for (int cg = 0; cg < 4; ++cg) {
            const f16* kr = Ks + (cg * 16 + l16) * 64;
            int c0 = quad ^ sw;
            half8 b0 = *(const half8*)(kr + c0 * 8);
            half8 b1 = *(const half8*)(kr + (c0 ^ 4) * 8);
            floatx4 z = {};
            sf[cg] = mfma16(aq1, b1, mfma16(aq0, b0, z));
        }
        #pragma unroll
        for (int cg = 0; cg < 4; ++cg) {
            float mk = mrow[kc + cg * 16 + l16] * (-1e9f);
            #pragma unroll
            for (int r = 0; r < 4; ++r) {
                float e = __expf(sf[cg][r] * scale + mk);
                lsum[r] += e;
                Ps[wv][(quad * 4 + r) * 40 + cg * 16 + l16] = (f16)e;
            }
        }
        half8 ap0 = *(const half8*)(Ps[wv] + l16 * 40 + quad * 8);
        half8 ap1 = *(const half8*)(Ps[wv] + l16 * 40 + 32 + quad * 8);
        #pragma unroll
        for (int td = 0; td < 4; ++td) {
            const f16* vr = Vs + (td * 16 + l16) * 64;
            int c0 = quad ^ sw;
            half8 bv0 = *(const half8*)(vr + c0 * 8);
            half8 bv1 = *(const half8*)(vr + (c0 ^ 4) * 8);
            o[td] = mfma16(ap0, bv0, o[td]);
            o[td] = mfma16(ap1, bv1, o[td]);
        }
    }

    #pragma unroll
    for (int r = 0; r < 4; ++r) {
        float s = lsum[r];
        s += __shfl_xor(s, 1); s += __shfl_xor(s, 2);
        s += __shfl_xor(s, 4); s += __shfl_xor(s, 8);
        lsum[r] = 1.f / s;
    }
    #pragma unroll
    for (int td = 0; td < 4; ++td)
        #pragma unroll
        for (int r = 0; r < 4; ++r)
            ctx[((size_t)b * 1024 + q0 + quad * 4 + r) * 1024 + h * 64 + td * 16 + l16]
                = (f16)(o[td][r] * lsum[r]);
}

// ---------------- launcher ---------------------------------------------------
extern "C" void kernel_launch(void* const* d_in, const int* in_sizes, int n_in,
                              void* d_out, int out_size, void* d_ws, size_t ws_size,
                              hipStream_t stream)
{
    const float* inputs = (const float*)d_in[0];
    const float* mask   = (const float*)d_in[1];
    const float* qkvw   = (const float*)d_in[2];
    const float* qkvb   = (const float*)d_in[3];
    const float* ow     = (const float*)d_in[4];
    const float* ob     = (const float*)d_in[5];
    const float* anw    = (const float*)d_in[6];
    const float* anb    = (const float*)d_in[7];
    const float* iw     = (const float*)d_in[8];
    const float* ib     = (const float*)d_in[9];
    const float* outw   = (const float*)d_in[10];
    const float* outb   = (const float*)d_in[11];
    const float* fnw    = (const float*)d_in[12];
    const float* fnb    = (const float*)d_in[13];
    float* out = (float*)d_out;

    const int M = 8192;
    uint8_t* ws = (uint8_t*)d_ws;
    f16* wT_qkv = (f16*)(ws + 0);                 //  6 MB [3072,1024]
    f16* wT_o   = (f16*)(ws + 6291456);           //  2 MB [1024,1024]
    f16* wT_i   = (f16*)(ws + 8388608);           //  8 MB [4096,1024]
    f16* wT_out = (f16*)(ws + 16777216);          //  8 MB [1024,4096]
    f16* xln    = (f16*)(ws + 25165824);          // 16 MB [8192,1024]
    float* x1   = (float*)(ws + 41943040);        // 32 MB fp32 [8192,1024]
    f16* qbuf   = (f16*)(ws + 75497472);          // 16 MB [b,h,s,d]
    f16* kbuf   = (f16*)(ws + 92274688);          // 16 MB [b,h,s,d]
    f16* vbuf   = (f16*)(ws + 109051904);         // 16 MB [b,h,d,s]
    f16* ctx    = (f16*)(ws + 125829120);         // 16 MB [8192,1024]
    f16* hbuf   = (f16*)(ws + 75497472);          // 64 MB [8192,4096] (aliases q/k/v/ctx, dead by then)

    transpose_f16_kernel<<<dim3(96, 32),  256, 0, stream>>>(qkvw, wT_qkv, 1024, 3072);
    transpose_f16_kernel<<<dim3(32, 32),  256, 0, stream>>>(ow,   wT_o,   1024, 1024);
    transpose_f16_kernel<<<dim3(128, 32), 256, 0, stream>>>(iw,   wT_i,   1024, 4096);
    transpose_f16_kernel<<<dim3(32, 128), 256, 0, stream>>>(outw, wT_out, 4096, 1024);

    ln_f16_kernel<<<8192, 256, 0, stream>>>(inputs, anw, anb, xln);

    gemm_big_kernel<2><<<dim3(32, 24), 256, 0, stream>>>(xln, wT_qkv, qkvb,
        nullptr, qbuf, kbuf, vbuf, M, 3072, 1024);

    attn_kernel<<<dim3(16, 16, 8), 256, 0, stream>>>(qbuf, kbuf, vbuf, mask, ctx);

    gemm_kernel<<<dim3(64, 8), 256, 0, stream>>>(ctx, wT_o, ob, inputs,
        x1, M, 1024, 1024);

    ln_f16_kernel<<<8192, 256, 0, stream>>>(x1, fnw, fnb, xln);

    gemm_big_kernel<1><<<dim3(32, 32), 256, 0, stream>>>(xln, wT_i, ib,
        hbuf, nullptr, nullptr, nullptr, M, 4096, 1024);

    gemm_kernel<<<dim3(64, 8), 256, 0, stream>>>(hbuf, wT_out, outb, x1,
        out, M, 1024, 4096);
}

// Round 7
// 478.312 us; speedup vs baseline: 1.0348x; 1.0348x over previous
//
#include <hip/hip_runtime.h>
#include <cstdint>
#include <cstddef>

typedef _Float16 f16;
typedef _Float16 half8 __attribute__((ext_vector_type(8)));
typedef _Float16 half4v __attribute__((ext_vector_type(4)));
typedef float floatx4 __attribute__((ext_vector_type(4)));
typedef float floatx16 __attribute__((ext_vector_type(16)));

__device__ __forceinline__ floatx4 mfma16(half8 a, half8 b, floatx4 c) {
    return __builtin_amdgcn_mfma_f32_16x16x32_f16(a, b, c, 0, 0, 0);
}
__device__ __forceinline__ floatx16 mfma32(half8 a, half8 b, floatx16 c) {
    return __builtin_amdgcn_mfma_f32_32x32x16_f16(a, b, c, 0, 0, 0);
}

// async global->LDS, 16B per lane; LDS dest is wave-uniform base + lane*16.
__device__ __forceinline__ void async16(const f16* g, f16* l) {
    __builtin_amdgcn_global_load_lds(
        (const __attribute__((address_space(1))) unsigned int*)(uintptr_t)g,
        (__attribute__((address_space(3))) unsigned int*)(uintptr_t)l,
        16, 0, 0);
}

// ---------------- LayerNorm (fp32 in -> f16 out), one block per row of 1024 ----
__global__ __launch_bounds__(256)
void ln_f16_kernel(const float* __restrict__ x, const float* __restrict__ g,
                   const float* __restrict__ be, f16* __restrict__ y)
{
    int row = blockIdx.x, t = threadIdx.x;
    const float* xr = x + (size_t)row * 1024;
    float4 v = *(const float4*)(xr + t * 4);
    float s1 = v.x + v.y + v.z + v.w;
    float s2 = v.x * v.x + v.y * v.y + v.z * v.z + v.w * v.w;
    #pragma unroll
    for (int off = 32; off >= 1; off >>= 1) {
        s1 += __shfl_xor(s1, off);
        s2 += __shfl_xor(s2, off);
    }
    __shared__ float r1[4], r2[4];
    if ((t & 63) == 0) { r1[t >> 6] = s1; r2[t >> 6] = s2; }
    __syncthreads();
    s1 = r1[0] + r1[1] + r1[2] + r1[3];
    s2 = r2[0] + r2[1] + r2[2] + r2[3];
    float mean = s1 * 0.0009765625f;
    float var  = s2 * 0.0009765625f - mean * mean;
    float rs = rsqrtf(var + 1e-6f);
    float4 gv = *(const float4*)(g + t * 4);
    float4 bv = *(const float4*)(be + t * 4);
    half4v o;
    o[0] = (f16)((v.x - mean) * rs * gv.x + bv.x);
    o[1] = (f16)((v.y - mean) * rs * gv.y + bv.y);
    o[2] = (f16)((v.z - mean) * rs * gv.z + bv.z);
    o[3] = (f16)((v.w - mean) * rs * gv.w + bv.w);
    *(half4v*)(y + (size_t)row * 1024 + t * 4) = o;
}

// ---------------- fp32 [R,C] -> f16 transpose [C,R] --------------------------
__global__ __launch_bounds__(256)
void transpose_f16_kernel(const float* __restrict__ W, f16* __restrict__ WT,
                          int R, int C)
{
    __shared__ float tile[32][33];
    int tx = threadIdx.x & 31, ty0 = threadIdx.x >> 5;
    int r0 = blockIdx.y * 32, c0 = blockIdx.x * 32;
    #pragma unroll
    for (int i = 0; i < 4; ++i)
        tile[ty0 + i * 8][tx] = W[(size_t)(r0 + ty0 + i * 8) * C + c0 + tx];
    __syncthreads();
    #pragma unroll
    for (int i = 0; i < 4; ++i)
        WT[(size_t)(c0 + ty0 + i * 8) * R + r0 + tx] = (f16)tile[tx][ty0 + i * 8];
}

// ---------------- GEMM small-N: C[M,N] = A * BT^T + bias; fp32 out += res ----
// 128x128 tile, BK=64, XOR-swizzled LDS. Double-buffered 2-phase pipeline.
// [R4 WINNER - DO NOT TOUCH]
__global__ __launch_bounds__(256, 2)
void gemm_kernel(const f16* __restrict__ A, const f16* __restrict__ BT,
                 const float* __restrict__ bias, const float* __restrict__ res,
                 float* __restrict__ Cf32, int M, int N, int K)
{
    __shared__ __align__(16) f16 As[2][128 * 64];
    __shared__ __align__(16) f16 Bs[2][128 * 64];
    int m0 = blockIdx.x * 128, n0 = blockIdx.y * 128;
    int t = threadIdx.x, lane = t & 63, wave = t >> 6;
    int quad = lane >> 4, l16 = lane & 15;
    int wm = (wave & 1) * 64, wn = (wave >> 1) * 64;
    int sw = l16 & 7;
    floatx4 acc[4][4] = {};

    // Per-thread staging sources (pre-swizzled) + wave-uniform LDS slots.
    const f16* gA[4]; const f16* gB[4]; int oS[4];
    #pragma unroll
    for (int c = 0; c < 4; ++c) {
        int s = c * 256 + t;
        int row = s >> 3, lg = (s & 7) ^ (row & 7);
        gA[c] = A  + (size_t)(m0 + row) * K + lg * 8;
        gB[c] = BT + (size_t)(n0 + row) * K + lg * 8;
        oS[c] = (c * 256 + (t & ~63)) * 8;
    }

    // Prologue: stage tile 0 into buffer 0.
    #pragma unroll
    for (int c = 0; c < 4; ++c) {
        async16(gA[c], As[0] + oS[c]);
        async16(gB[c], Bs[0] + oS[c]);
    }
    __syncthreads();                       // vmcnt(0) drain + barrier

    int buf = 0;
    for (int k0 = 0; k0 < K; k0 += 64) {
        int kn = k0 + 64;
        if (kn < K) {                      // issue NEXT tile's staging first
            #pragma unroll
            for (int c = 0; c < 4; ++c) {
                async16(gA[c] + kn, As[buf ^ 1] + oS[c]);
                async16(gB[c] + kn, Bs[buf ^ 1] + oS[c]);
            }
        }
        // Compute current tile (resident in As[buf]/Bs[buf]).
        #pragma unroll
        for (int ks = 0; ks < 2; ++ks) {
            int ca = (ks * 4 + quad) ^ sw;
            half8 a[4], b[4];
            #pragma unroll
            for (int i = 0; i < 4; ++i) {
                a[i] = *(const half8*)(As[buf] + (wm + i * 16 + l16) * 64 + ca * 8);
                b[i] = *(const half8*)(Bs[buf] + (wn + i * 16 + l16) * 64 + ca * 8);
            }
            #pragma unroll
            for (int i = 0; i < 4; ++i)
                #pragma unroll
                for (int j = 0; j < 4; ++j)
                    acc[i][j] = mfma16(a[i], b[j], acc[i][j]);
        }
        __syncthreads();                   // waits next tile's loads + barrier
        buf ^= 1;
    }

    #pragma unroll
    for (int j = 0; j < 4; ++j) {
        int col = n0 + wn + j * 16 + l16;
        float bv = bias[col];
        #pragma unroll
        for (int i = 0; i < 4; ++i) {
            int rowb = m0 + wm + i * 16 + quad * 4;
            #pragma unroll
            for (int r = 0; r < 4; ++r) {
                float v = acc[i][j][r] + bv;
                size_t idx = (size_t)(rowb + r) * N + col;
                Cf32[idx] = v + res[idx];
            }
        }
    }
}

// ---------------- GEMM big-tile: 256x128, BK=32, 32x32x16 MFMA ---------------
// Triple-buffered (3x24KB=72KB -> 2 blocks/CU), prefetch distance 2, counted
// vmcnt(6) + raw s_barrier (T3+T4): the wait at each tile boundary is for loads
// issued two compute-phases (~1000+ cyc) earlier -> drain latency ~fully hidden
// (R6's distance-1 dbuf exposed ~400 cyc/tile). setprio(1) around MFMA (T5).
// MODE 1: f16 out + ReLU.  MODE 2: QKV scatter (Q,K->[b,h,s,d]; V->[b,h,d,s]).
#define BSTAGE(bi, kk) do {                                                    \
    _Pragma("unroll")                                                          \
    for (int c = 0; c < 4; ++c) async16(gA[c] + (kk), As[bi] + oA[c]);         \
    _Pragma("unroll")                                                          \
    for (int c = 0; c < 2; ++c) async16(gB[c] + (kk), Bs[bi] + oB[c]);         \
} while (0)

template<int MODE>
__global__ __launch_bounds__(256, 2)
void gemm_big_kernel(const f16* __restrict__ A, const f16* __restrict__ BT,
                     const float* __restrict__ bias, f16* __restrict__ Cf16,
                     f16* __restrict__ qb, f16* __restrict__ kb, f16* __restrict__ vb,
                     int M, int N, int K)
{
    __shared__ __align__(16) f16 As[3][256 * 32];   // 16 KB each
    __shared__ __align__(16) f16 Bs[3][128 * 32];   //  8 KB each
    int m0 = blockIdx.x * 256, n0 = blockIdx.y * 128;
    int t = threadIdx.x, lane = t & 63, wave = t >> 6;
    int l32 = lane & 31, kg = lane >> 5;             // k-group (0/1)
    int swz = (l32 ^ (l32 >> 2) ^ (l32 >> 4)) & 3;   // s2(l32)
    floatx16 acc[2][4];
    #pragma unroll
    for (int mi = 0; mi < 2; ++mi)
        #pragma unroll
        for (int jn = 0; jn < 4; ++jn)
            #pragma unroll
            for (int r = 0; r < 16; ++r) acc[mi][jn][r] = 0.f;

    // Per-thread staging sources (pre-swizzled with s2) + wave-uniform slots.
    const f16* gA[4]; int oA[4];
    #pragma unroll
    for (int c = 0; c < 4; ++c) {
        int s = c * 256 + t;
        int row = s >> 2, phys = s & 3;
        int lg = phys ^ ((row ^ (row >> 2) ^ (row >> 4)) & 3);
        gA[c] = A + (size_t)(m0 + row) * K + lg * 8;
        oA[c] = (c * 256 + (t & ~63)) * 8;
    }
    const f16* gB[2]; int oB[2];
    #pragma unroll
    for (int c = 0; c < 2; ++c) {
        int s = c * 256 + t;
        int row = s >> 2, phys = s & 3;
        int lg = phys ^ ((row ^ (row >> 2) ^ (row >> 4)) & 3);
        gB[c] = BT + (size_t)(n0 + row) * K + lg * 8;
        oB[c] = (c * 256 + (t & ~63)) * 8;
    }

    // Prologue: stage tiles 0 and 1 (6 loads each, FIFO per-wave).
    BSTAGE(0, 0);
    BSTAGE(1, 32);
    asm volatile("s_waitcnt vmcnt(6)" ::: "memory");   // tile 0 landed
    __builtin_amdgcn_s_barrier();

    int bi = 0;
    #pragma unroll 1
    for (int k0 = 0; k0 < K; k0 += 32) {
        int kn = k0 + 64;
        int bs = bi + 2; if (bs >= 3) bs -= 3;
        if (kn < K) BSTAGE(bs, kn);        // prefetch distance 2
        // Compute current tile: 2 sub-steps of k16.
        #pragma unroll
        for (int ss = 0; ss < 2; ++ss) {
            int cb = ss * 2 + kg;
            half8 a[2], b[4];
            #pragma unroll
            for (int mi = 0; mi < 2; ++mi) {
                int ca = (cb ^ swz ^ (mi * 2));            // +s2 of row-base
                a[mi] = *(const half8*)(As[bi] + (wave * 64 + mi * 32 + l32) * 32 + ca * 8);
            }
            #pragma unroll
            for (int jn = 0; jn < 4; ++jn) {
                int ca = (cb ^ swz ^ ((jn & 1) * 2));
                b[jn] = *(const half8*)(Bs[bi] + (jn * 32 + l32) * 32 + ca * 8);
            }
            __builtin_amdgcn_s_setprio(1);
            #pragma unroll
            for (int mi = 0; mi < 2; ++mi)
                #pragma unroll
                for (int jn = 0; jn < 4; ++jn)
                    acc[mi][jn] = mfma32(a[mi], b[jn], acc[mi][jn]);
            __builtin_amdgcn_s_setprio(0);
        }
        // Counted wait: tile t+1's 6 loads landed; t+2's 6 stay in flight.
        if (kn < K) { asm volatile("s_waitcnt vmcnt(6)" ::: "memory"); }
        else        { asm volatile("s_waitcnt vmcnt(0)" ::: "memory"); }
        __builtin_amdgcn_s_barrier();
        bi = bi + 1; if (bi >= 3) bi = 0;
    }

    // C/D layout (32x32): col = lane&31, row = (reg&3) + 8*(reg>>2) + 4*(lane>>5)
    #pragma unroll
    for (int mi = 0; mi < 2; ++mi) {
        int mbase = m0 + wave * 64 + mi * 32 + 4 * kg;
        #pragma unroll
        for (int jn = 0; jn < 4; ++jn) {
            int col = n0 + jn * 32 + l32;
            float bv = bias[col];
            if (MODE == 1) {
                #pragma unroll
                for (int reg = 0; reg < 16; ++reg) {
                    int row = mbase + (reg & 3) + 8 * (reg >> 2);
                    Cf16[(size_t)row * N + col] = (f16)fmaxf(acc[mi][jn][reg] + bv, 0.f);
                }
            } else {
                int part = col >> 10;
                int h = (col >> 6) & 15;
                int d = col & 63;
                if (part == 2) {
                    #pragma unroll
                    for (int rb = 0; rb < 4; ++rb) {
                        int m = mbase + 8 * rb;
                        int bb = m >> 10, s = m & 1023;
                        size_t bh = (size_t)bb * 16 + h;
                        half4v pv;
                        #pragma unroll
                        for (int r = 0; r < 4; ++r) pv[r] = (f16)(acc[mi][jn][rb * 4 + r] + bv);
                        *(half4v*)(vb + (bh * 64 + d) * 1024 + s) = pv;
                    }
                } else {
                    f16* dst0 = part == 0 ? qb : kb;
                    #pragma unroll
                    for (int reg = 0; reg < 16; ++reg) {
                        int m = mbase + (reg & 3) + 8 * (reg >> 2);
                        int bb = m >> 10, s = m & 1023;
                        size_t bh = (size_t)bb * 16 + h;
                        dst0[(bh * 1024 + s) * 64 + d] = (f16)(acc[mi][jn][reg] + bv);
                    }
                }
            }
        }
    }
}
#undef BSTAGE

// ---------------- Flash attention v3 ----------------------------------------
__global__ __launch_bounds__(256)
void attn_kernel(const f16* __restrict__ qb, const f16* __restrict__ kb,
                 const f16* __restrict__ vb, const float* __restrict__ mask,
                 f16* __restrict__ ctx)
{
    const int S = 1024;
    int qt = blockIdx.x, h = blockIdx.y, b = blockIdx.z;
    size_t bh = (size_t)b * 16 + h;
    int t = threadIdx.x, lane = t & 63, wv = t >> 6;
    int quad = lane >> 4, l16 = lane & 15;
    int sw = l16 & 7;

    __shared__ __align__(16) f16 Ks[64 * 64];
    __shared__ __align__(16) f16 Vs[64 * 64];
    __shared__ __align__(16) f16 Ps[4][16 * 40];

    int q0 = qt * 64 + wv * 16;
    const f16* qrow = qb + (bh * 1024 + q0 + l16) * 64;
    half8 aq0 = *(const half8*)(qrow + quad * 8);
    half8 aq1 = *(const half8*)(qrow + 32 + quad * 8);

    floatx4 o[4] = {};
    float lsum[4] = {0.f, 0.f, 0.f, 0.f};
    const float scale = 0.125f;
    const float* mrow = mask + b * S;

    for (int kc = 0; kc < S; kc += 64) {
        __syncthreads();
        #pragma unroll
        for (int c = 0; c < 2; ++c) {
            int s = c * 256 + t;
            int row = s >> 3, phys = s & 7;
            int lg = phys ^ (row & 7);
            f16* lk = Ks + (size_t)(c * 256 + (t & ~63)) * 8;
            f16* lv = Vs + (size_t)(c * 256 + (t & ~63)) * 8;
            async16(kb + (bh * 1024 + kc + row) * 64 + lg * 8, lk);
            async16(vb + (bh * 64 + row) * 1024 + kc + lg * 8, lv);
        }
        __syncthreads();

        floatx4 sf[4];
        #pragma unroll
        for (int cg = 0; cg < 4; ++cg) {
            const f16* kr = Ks + (cg * 16 + l16) * 64;
            int c0 = quad ^ sw;
            half8 b0 = *(const half8*)(kr + c0 * 8);
            half8 b1 = *(const half8*)(kr + (c0 ^ 4) * 8);
            floatx4 z = {};
            sf[cg] = mfma16(aq1, b1, mfma16(aq0, b0, z));
        }
        #pragma unroll
        for (int cg = 0; cg < 4; ++cg) {
            float mk = mrow[kc + cg * 16 + l16] * (-1e9f);
            #pragma unroll
            for (int r = 0; r < 4; ++r) {
                float e = __expf(sf[cg][r] * scale + mk);
                lsum[r] += e;
                Ps[wv][(quad * 4 + r) * 40 + cg * 16 + l16] = (f16)e;
            }
        }
        half8 ap0 = *(const half8*)(Ps[wv] + l16 * 40 + quad * 8);
        half8 ap1 = *(const half8*)(Ps[wv] + l16 * 40 + 32 + quad * 8);
        #pragma unroll
        for (int td = 0; td < 4; ++td) {
            const f16* vr = Vs + (td * 16 + l16) * 64;
            int c0 = quad ^ sw;
            half8 bv0 = *(const half8*)(vr + c0 * 8);
            half8 bv1 = *(const half8*)(vr + (c0 ^ 4) * 8);
            o[td] = mfma16(ap0, bv0, o[td]);
            o[td] = mfma16(ap1, bv1, o[td]);
        }
    }

    #pragma unroll
    for (int r = 0; r < 4; ++r) {
        float s = lsum[r];
        s += __shfl_xor(s, 1); s += __shfl_xor(s, 2);
        s += __shfl_xor(s, 4); s += __shfl_xor(s, 8);
        lsum[r] = 1.f / s;
    }
    #pragma unroll
    for (int td = 0; td < 4; ++td)
        #pragma unroll
        for (int r = 0; r < 4; ++r)
            ctx[((size_t)b * 1024 + q0 + quad * 4 + r) * 1024 + h * 64 + td * 16 + l16]
                = (f16)(o[td][r] * lsum[r]);
}

// ---------------- launcher ---------------------------------------------------
extern "C" void kernel_launch(void* const* d_in, const int* in_sizes, int n_in,
                              void* d_out, int out_size, void* d_ws, size_t ws_size,
                              hipStream_t stream)
{
    const float* inputs = (const float*)d_in[0];
    const float* mask   = (const float*)d_in[1];
    const float* qkvw   = (const float*)d_in[2];
    const float* qkvb   = (const float*)d_in[3];
    const float* ow     = (const float*)d_in[4];
    const float* ob     = (const float*)d_in[5];
    const float* anw    = (const float*)d_in[6];
    const float* anb    = (const float*)d_in[7];
    const float* iw     = (const float*)d_in[8];
    const float* ib     = (const float*)d_in[9];
    const float* outw   = (const float*)d_in[10];
    const float* outb   = (const float*)d_in[11];
    const float* fnw    = (const float*)d_in[12];
    const float* fnb    = (const float*)d_in[13];
    float* out = (float*)d_out;

    const int M = 8192;
    uint8_t* ws = (uint8_t*)d_ws;
    f16* wT_qkv = (f16*)(ws + 0);                 //  6 MB [3072,1024]
    f16* wT_o   = (f16*)(ws + 6291456);           //  2 MB [1024,1024]
    f16* wT_i   = (f16*)(ws + 8388608);           //  8 MB [4096,1024]
    f16* wT_out = (f16*)(ws + 16777216);          //  8 MB [1024,4096]
    f16* xln    = (f16*)(ws + 25165824);          // 16 MB [8192,1024]
    float* x1   = (float*)(ws + 41943040);        // 32 MB fp32 [8192,1024]
    f16* qbuf   = (f16*)(ws + 75497472);          // 16 MB [b,h,s,d]
    f16* kbuf   = (f16*)(ws + 92274688);          // 16 MB [b,h,s,d]
    f16* vbuf   = (f16*)(ws + 109051904);         // 16 MB [b,h,d,s]
    f16* ctx    = (f16*)(ws + 125829120);         // 16 MB [8192,1024]
    f16* hbuf   = (f16*)(ws + 75497472);          // 64 MB [8192,4096] (aliases q/k/v/ctx, dead by then)

    transpose_f16_kernel<<<dim3(96, 32),  256, 0, stream>>>(qkvw, wT_qkv, 1024, 3072);
    transpose_f16_kernel<<<dim3(32, 32),  256, 0, stream>>>(ow,   wT_o,   1024, 1024);
    transpose_f16_kernel<<<dim3(128, 32), 256, 0, stream>>>(iw,   wT_i,   1024, 4096);
    transpose_f16_kernel<<<dim3(32, 128), 256, 0, stream>>>(outw, wT_out, 4096, 1024);

    ln_f16_kernel<<<8192, 256, 0, stream>>>(inputs, anw, anb, xln);

    gemm_big_kernel<2><<<dim3(32, 24), 256, 0, stream>>>(xln, wT_qkv, qkvb,
        nullptr, qbuf, kbuf, vbuf, M, 3072, 1024);

    attn_kernel<<<dim3(16, 16, 8), 256, 0, stream>>>(qbuf, kbuf, vbuf, mask, ctx);

    gemm_kernel<<<dim3(64, 8), 256, 0, stream>>>(ctx, wT_o, ob, inputs,
        x1, M, 1024, 1024);

    ln_f16_kernel<<<8192, 256, 0, stream>>>(x1, fnw, fnb, xln);

    gemm_big_kernel<1><<<dim3(32, 32), 256, 0, stream>>>(xln, wT_i, ib,
        hbuf, nullptr, nullptr, nullptr, M, 4096, 1024);

    gemm_kernel<<<dim3(64, 8), 256, 0, stream>>>(hbuf, wT_out, outb, x1,
        out, M, 1024, 4096);
}

// Round 8
// 464.540 us; speedup vs baseline: 1.0654x; 1.0296x over previous
//
#include <hip/hip_runtime.h>
#include <cstdint>
#include <cstddef>

typedef _Float16 f16;
typedef _Float16 half8 __attribute__((ext_vector_type(8)));
typedef _Float16 half4v __attribute__((ext_vector_type(4)));
typedef float floatx4 __attribute__((ext_vector_type(4)));
typedef float floatx16 __attribute__((ext_vector_type(16)));

__device__ __forceinline__ floatx4 mfma16(half8 a, half8 b, floatx4 c) {
    return __builtin_amdgcn_mfma_f32_16x16x32_f16(a, b, c, 0, 0, 0);
}
__device__ __forceinline__ floatx16 mfma32(half8 a, half8 b, floatx16 c) {
    return __builtin_amdgcn_mfma_f32_32x32x16_f16(a, b, c, 0, 0, 0);
}

// async global->LDS, 16B per lane; LDS dest is wave-uniform base + lane*16.
__device__ __forceinline__ void async16(const f16* g, f16* l) {
    __builtin_amdgcn_global_load_lds(
        (const __attribute__((address_space(1))) unsigned int*)(uintptr_t)g,
        (__attribute__((address_space(3))) unsigned int*)(uintptr_t)l,
        16, 0, 0);
}

// ---------------- LayerNorm (fp32 in -> f16 out), one block per row of 1024 ----
__global__ __launch_bounds__(256)
void ln_f16_kernel(const float* __restrict__ x, const float* __restrict__ g,
                   const float* __restrict__ be, f16* __restrict__ y)
{
    int row = blockIdx.x, t = threadIdx.x;
    const float* xr = x + (size_t)row * 1024;
    float4 v = *(const float4*)(xr + t * 4);
    float s1 = v.x + v.y + v.z + v.w;
    float s2 = v.x * v.x + v.y * v.y + v.z * v.z + v.w * v.w;
    #pragma unroll
    for (int off = 32; off >= 1; off >>= 1) {
        s1 += __shfl_xor(s1, off);
        s2 += __shfl_xor(s2, off);
    }
    __shared__ float r1[4], r2[4];
    if ((t & 63) == 0) { r1[t >> 6] = s1; r2[t >> 6] = s2; }
    __syncthreads();
    s1 = r1[0] + r1[1] + r1[2] + r1[3];
    s2 = r2[0] + r2[1] + r2[2] + r2[3];
    float mean = s1 * 0.0009765625f;
    float var  = s2 * 0.0009765625f - mean * mean;
    float rs = rsqrtf(var + 1e-6f);
    float4 gv = *(const float4*)(g + t * 4);
    float4 bv = *(const float4*)(be + t * 4);
    half4v o;
    o[0] = (f16)((v.x - mean) * rs * gv.x + bv.x);
    o[1] = (f16)((v.y - mean) * rs * gv.y + bv.y);
    o[2] = (f16)((v.z - mean) * rs * gv.z + bv.z);
    o[3] = (f16)((v.w - mean) * rs * gv.w + bv.w);
    *(half4v*)(y + (size_t)row * 1024 + t * 4) = o;
}

// ---------------- fp32 [R,C] -> f16 transpose [C,R] --------------------------
__global__ __launch_bounds__(256)
void transpose_f16_kernel(const float* __restrict__ W, f16* __restrict__ WT,
                          int R, int C)
{
    __shared__ float tile[32][33];
    int tx = threadIdx.x & 31, ty0 = threadIdx.x >> 5;
    int r0 = blockIdx.y * 32, c0 = blockIdx.x * 32;
    #pragma unroll
    for (int i = 0; i < 4; ++i)
        tile[ty0 + i * 8][tx] = W[(size_t)(r0 + ty0 + i * 8) * C + c0 + tx];
    __syncthreads();
    #pragma unroll
    for (int i = 0; i < 4; ++i)
        WT[(size_t)(c0 + ty0 + i * 8) * R + r0 + tx] = (f16)tile[tx][ty0 + i * 8];
}

// ---------------- GEMM small-N: C[M,N] = A * BT^T + bias; fp32 out += res ----
// 128x128 tile, BK=64, XOR-swizzled LDS. Double-buffered 2-phase pipeline.
// [R4 WINNER - DO NOT TOUCH]
__global__ __launch_bounds__(256, 2)
void gemm_kernel(const f16* __restrict__ A, const f16* __restrict__ BT,
                 const float* __restrict__ bias, const float* __restrict__ res,
                 float* __restrict__ Cf32, int M, int N, int K)
{
    __shared__ __align__(16) f16 As[2][128 * 64];
    __shared__ __align__(16) f16 Bs[2][128 * 64];
    int m0 = blockIdx.x * 128, n0 = blockIdx.y * 128;
    int t = threadIdx.x, lane = t & 63, wave = t >> 6;
    int quad = lane >> 4, l16 = lane & 15;
    int wm = (wave & 1) * 64, wn = (wave >> 1) * 64;
    int sw = l16 & 7;
    floatx4 acc[4][4] = {};

    // Per-thread staging sources (pre-swizzled) + wave-uniform LDS slots.
    const f16* gA[4]; const f16* gB[4]; int oS[4];
    #pragma unroll
    for (int c = 0; c < 4; ++c) {
        int s = c * 256 + t;
        int row = s >> 3, lg = (s & 7) ^ (row & 7);
        gA[c] = A  + (size_t)(m0 + row) * K + lg * 8;
        gB[c] = BT + (size_t)(n0 + row) * K + lg * 8;
        oS[c] = (c * 256 + (t & ~63)) * 8;
    }

    // Prologue: stage tile 0 into buffer 0.
    #pragma unroll
    for (int c = 0; c < 4; ++c) {
        async16(gA[c], As[0] + oS[c]);
        async16(gB[c], Bs[0] + oS[c]);
    }
    __syncthreads();                       // vmcnt(0) drain + barrier

    int buf = 0;
    for (int k0 = 0; k0 < K; k0 += 64) {
        int kn = k0 + 64;
        if (kn < K) {                      // issue NEXT tile's staging first
            #pragma unroll
            for (int c = 0; c < 4; ++c) {
                async16(gA[c] + kn, As[buf ^ 1] + oS[c]);
                async16(gB[c] + kn, Bs[buf ^ 1] + oS[c]);
            }
        }
        // Compute current tile (resident in As[buf]/Bs[buf]).
        #pragma unroll
        for (int ks = 0; ks < 2; ++ks) {
            int ca = (ks * 4 + quad) ^ sw;
            half8 a[4], b[4];
            #pragma unroll
            for (int i = 0; i < 4; ++i) {
                a[i] = *(const half8*)(As[buf] + (wm + i * 16 + l16) * 64 + ca * 8);
                b[i] = *(const half8*)(Bs[buf] + (wn + i * 16 + l16) * 64 + ca * 8);
            }
            #pragma unroll
            for (int i = 0; i < 4; ++i)
                #pragma unroll
                for (int j = 0; j < 4; ++j)
                    acc[i][j] = mfma16(a[i], b[j], acc[i][j]);
        }
        __syncthreads();                   // waits next tile's loads + barrier
        buf ^= 1;
    }

    #pragma unroll
    for (int j = 0; j < 4; ++j) {
        int col = n0 + wn + j * 16 + l16;
        float bv = bias[col];
        #pragma unroll
        for (int i = 0; i < 4; ++i) {
            int rowb = m0 + wm + i * 16 + quad * 4;
            #pragma unroll
            for (int r = 0; r < 4; ++r) {
                float v = acc[i][j][r] + bv;
                size_t idx = (size_t)(rowb + r) * N + col;
                Cf32[idx] = v + res[idx];
            }
        }
    }
}

// ---------------- GEMM big-tile: 256x128, BK=32, 32x32x16 MFMA ---------------
// [R6 WINNER - reverted from R7's triple-buffer experiment]
// 4 waves, each 64x128 (2x4 frags). 2-phase prefetch pipeline, BK=32, 48 KB
// double buffer -> 2 blocks/CU (2 waves/SIMD). s2 swizzle.
// MODE 1: f16 out + ReLU.  MODE 2: QKV scatter (Q,K->[b,h,s,d]; V->[b,h,d,s]).
template<int MODE>
__global__ __launch_bounds__(256, 2)
void gemm_big_kernel(const f16* __restrict__ A, const f16* __restrict__ BT,
                     const float* __restrict__ bias, f16* __restrict__ Cf16,
                     f16* __restrict__ qb, f16* __restrict__ kb, f16* __restrict__ vb,
                     int M, int N, int K)
{
    __shared__ __align__(16) f16 As[2][256 * 32];   // 16 KB each
    __shared__ __align__(16) f16 Bs[2][128 * 32];   //  8 KB each
    int m0 = blockIdx.x * 256, n0 = blockIdx.y * 128;
    int t = threadIdx.x, lane = t & 63, wave = t >> 6;
    int l32 = lane & 31, kg = lane >> 5;             // k-group (0/1)
    int swz = (l32 ^ (l32 >> 2) ^ (l32 >> 4)) & 3;   // s2(l32)
    floatx16 acc[2][4];
    #pragma unroll
    for (int mi = 0; mi < 2; ++mi)
        #pragma unroll
        for (int jn = 0; jn < 4; ++jn)
            #pragma unroll
            for (int r = 0; r < 16; ++r) acc[mi][jn][r] = 0.f;

    // Per-thread staging sources (pre-swizzled with s2) + wave-uniform slots.
    const f16* gA[4]; int oA[4];
    #pragma unroll
    for (int c = 0; c < 4; ++c) {
        int s = c * 256 + t;
        int row = s >> 2, phys = s & 3;
        int lg = phys ^ ((row ^ (row >> 2) ^ (row >> 4)) & 3);
        gA[c] = A + (size_t)(m0 + row) * K + lg * 8;
        oA[c] = (c * 256 + (t & ~63)) * 8;
    }
    const f16* gB[2]; int oB[2];
    #pragma unroll
    for (int c = 0; c < 2; ++c) {
        int s = c * 256 + t;
        int row = s >> 2, phys = s & 3;
        int lg = phys ^ ((row ^ (row >> 2) ^ (row >> 4)) & 3);
        gB[c] = BT + (size_t)(n0 + row) * K + lg * 8;
        oB[c] = (c * 256 + (t & ~63)) * 8;
    }

    // Prologue: stage tile 0 into buffer 0.
    #pragma unroll
    for (int c = 0; c < 4; ++c) async16(gA[c], As[0] + oA[c]);
    #pragma unroll
    for (int c = 0; c < 2; ++c) async16(gB[c], Bs[0] + oB[c]);
    __syncthreads();                       // vmcnt(0) drain + barrier

    int buf = 0;
    for (int k0 = 0; k0 < K; k0 += 32) {
        int kn = k0 + 32;
        if (kn < K) {                      // issue NEXT tile's staging first
            #pragma unroll
            for (int c = 0; c < 4; ++c) async16(gA[c] + kn, As[buf ^ 1] + oA[c]);
            #pragma unroll
            for (int c = 0; c < 2; ++c) async16(gB[c] + kn, Bs[buf ^ 1] + oB[c]);
        }
        // Compute current tile: 2 sub-steps of k16.
        #pragma unroll
        for (int ss = 0; ss < 2; ++ss) {
            int cb = ss * 2 + kg;
            half8 a[2], b[4];
            #pragma unroll
            for (int mi = 0; mi < 2; ++mi) {
                int ca = (cb ^ swz ^ (mi * 2));            // +s2 of row-base
                a[mi] = *(const half8*)(As[buf] + (wave * 64 + mi * 32 + l32) * 32 + ca * 8);
            }
            #pragma unroll
            for (int jn = 0; jn < 4; ++jn) {
                int ca = (cb ^ swz ^ ((jn & 1) * 2));
                b[jn] = *(const half8*)(Bs[buf] + (jn * 32 + l32) * 32 + ca * 8);
            }
            #pragma unroll
            for (int mi = 0; mi < 2; ++mi)
                #pragma unroll
                for (int jn = 0; jn < 4; ++jn)
                    acc[mi][jn] = mfma32(a[mi], b[jn], acc[mi][jn]);
        }
        __syncthreads();                   // waits next tile's loads + barrier
        buf ^= 1;
    }

    // C/D layout (32x32): col = lane&31, row = (reg&3) + 8*(reg>>2) + 4*(lane>>5)
    #pragma unroll
    for (int mi = 0; mi < 2; ++mi) {
        int mbase = m0 + wave * 64 + mi * 32 + 4 * kg;
        #pragma unroll
        for (int jn = 0; jn < 4; ++jn) {
            int col = n0 + jn * 32 + l32;
            float bv = bias[col];
            if (MODE == 1) {
                #pragma unroll
                for (int reg = 0; reg < 16; ++reg) {
                    int row = mbase + (reg & 3) + 8 * (reg >> 2);
                    Cf16[(size_t)row * N + col] = (f16)fmaxf(acc[mi][jn][reg] + bv, 0.f);
                }
            } else {
                int part = col >> 10;
                int h = (col >> 6) & 15;
                int d = col & 63;
                if (part == 2) {
                    #pragma unroll
                    for (int rb = 0; rb < 4; ++rb) {
                        int m = mbase + 8 * rb;
                        int bb = m >> 10, s = m & 1023;
                        size_t bh = (size_t)bb * 16 + h;
                        half4v pv;
                        #pragma unroll
                        for (int r = 0; r < 4; ++r) pv[r] = (f16)(acc[mi][jn][rb * 4 + r] + bv);
                        *(half4v*)(vb + (bh * 64 + d) * 1024 + s) = pv;
                    }
                } else {
                    f16* dst0 = part == 0 ? qb : kb;
                    #pragma unroll
                    for (int reg = 0; reg < 16; ++reg) {
                        int m = mbase + (reg & 3) + 8 * (reg >> 2);
                        int bb = m >> 10, s = m & 1023;
                        size_t bh = (size_t)bb * 16 + h;
                        dst0[(bh * 1024 + s) * 64 + d] = (f16)(acc[mi][jn][reg] + bv);
                    }
                }
            }
        }
    }
}

// ---------------- Flash attention v3 + 2-phase K/V prefetch ------------------
// R4-proven transform applied to the attn inner loop: Ks/Vs double-buffered
// (21->37 KB LDS, still 4 blocks/CU), tile t+1's staging issued BEFORE tile
// t's QK/softmax/PV compute (>=1500 cyc of cover), one __syncthreads per tile.
__global__ __launch_bounds__(256)
void attn_kernel(const f16* __restrict__ qb, const f16* __restrict__ kb,
                 const f16* __restrict__ vb, const float* __restrict__ mask,
                 f16* __restrict__ ctx)
{
    const int S = 1024;
    int qt = blockIdx.x, h = blockIdx.y, b = blockIdx.z;
    size_t bh = (size_t)b * 16 + h;
    int t = threadIdx.x, lane = t & 63, wv = t >> 6;
    int quad = lane >> 4, l16 = lane & 15;
    int sw = l16 & 7;

    __shared__ __align__(16) f16 Ks[2][64 * 64];
    __shared__ __align__(16) f16 Vs[2][64 * 64];
    __shared__ __align__(16) f16 Ps[4][16 * 40];

    int q0 = qt * 64 + wv * 16;
    const f16* qrow = qb + (bh * 1024 + q0 + l16) * 64;
    half8 aq0 = *(const half8*)(qrow + quad * 8);
    half8 aq1 = *(const half8*)(qrow + 32 + quad * 8);

    floatx4 o[4] = {};
    float lsum[4] = {0.f, 0.f, 0.f, 0.f};
    const float scale = 0.125f;
    const float* mrow = mask + b * S;

    // Per-thread staging sources (pre-swizzled) + wave-uniform LDS slots.
    const f16* pK[2]; const f16* pV[2]; int oS[2];
    #pragma unroll
    for (int c = 0; c < 2; ++c) {
        int s = c * 256 + t;
        int row = s >> 3, lg = (s & 7) ^ (row & 7);
        pK[c] = kb + (bh * 1024 + row) * 64 + lg * 8;   // +kc*64 per tile
        pV[c] = vb + (bh * 64 + row) * 1024 + lg * 8;   // +kc    per tile
        oS[c] = (c * 256 + (t & ~63)) * 8;
    }

    // Prologue: stage tile 0 into buffer 0.
    #pragma unroll
    for (int c = 0; c < 2; ++c) {
        async16(pK[c], Ks[0] + oS[c]);
        async16(pV[c], Vs[0] + oS[c]);
    }
    __syncthreads();                       // vmcnt(0) drain + barrier

    int buf = 0;
    for (int kc = 0; kc < S; kc += 64) {
        int kn = kc + 64;
        if (kn < S) {                      // issue NEXT tile's staging first
            #pragma unroll
            for (int c = 0; c < 2; ++c) {
                async16(pK[c] + (size_t)kn * 64, Ks[buf ^ 1] + oS[c]);
                async16(pV[c] + kn,              Vs[buf ^ 1] + oS[c]);
            }
        }

        floatx4 sf[4];
        #pragma unroll
        for (int cg = 0; cg < 4; ++cg) {
            const f16* kr = Ks[buf] + (cg * 16 + l16) * 64;
            int c0 = quad ^ sw;
            half8 b0 = *(const half8*)(kr + c0 * 8);
            half8 b1 = *(const half8*)(kr + (c0 ^ 4) * 8);
            floatx4 z = {};
            sf[cg] = mfma16(aq1, b1, mfma16(aq0, b0, z));
        }
        #pragma unroll
        for (int cg = 0; cg < 4; ++cg) {
            float mk = mrow[kc + cg * 16 + l16] * (-1e9f);
            #pragma unroll
            for (int r = 0; r < 4; ++r) {
                float e = __expf(sf[cg][r] * scale + mk);
                lsum[r] += e;
                Ps[wv][(quad * 4 + r) * 40 + cg * 16 + l16] = (f16)e;
            }
        }
        half8 ap0 = *(const half8*)(Ps[wv] + l16 * 40 + quad * 8);
        half8 ap1 = *(const half8*)(Ps[wv] + l16 * 40 + 32 + quad * 8);
        #pragma unroll
        for (int td = 0; td < 4; ++td) {
            const f16* vr = Vs[buf] + (td * 16 + l16) * 64;
            int c0 = quad ^ sw;
            half8 bv0 = *(const half8*)(vr + c0 * 8);
            half8 bv1 = *(const half8*)(vr + (c0 ^ 4) * 8);
            o[td] = mfma16(ap0, bv0, o[td]);
            o[td] = mfma16(ap1, bv1, o[td]);
        }
        __syncthreads();                   // waits next tile's loads + barrier
        buf ^= 1;
    }

    #pragma unroll
    for (int r = 0; r < 4; ++r) {
        float s = lsum[r];
        s += __shfl_xor(s, 1); s += __shfl_xor(s, 2);
        s += __shfl_xor(s, 4); s += __shfl_xor(s, 8);
        lsum[r] = 1.f / s;
    }
    #pragma unroll
    for (int td = 0; td < 4; ++td)
        #pragma unroll
        for (int r = 0; r < 4; ++r)
            ctx[((size_t)b * 1024 + q0 + quad * 4 + r) * 1024 + h * 64 + td * 16 + l16]
                = (f16)(o[td][r] * lsum[r]);
}

// ---------------- launcher ---------------------------------------------------
extern "C" void kernel_launch(void* const* d_in, const int* in_sizes, int n_in,
                              void* d_out, int out_size, void* d_ws, size_t ws_size,
                              hipStream_t stream)
{
    const float* inputs = (const float*)d_in[0];
    const float* mask   = (const float*)d_in[1];
    const float* qkvw   = (const float*)d_in[2];
    const float* qkvb   = (const float*)d_in[3];
    const float* ow     = (const float*)d_in[4];
    const float* ob     = (const float*)d_in[5];
    const float* anw    = (const float*)d_in[6];
    const float* anb    = (const float*)d_in[7];
    const float* iw     = (const float*)d_in[8];
    const float* ib     = (const float*)d_in[9];
    const float* outw   = (const float*)d_in[10];
    const float* outb   = (const float*)d_in[11];
    const float* fnw    = (const float*)d_in[12];
    const float* fnb    = (const float*)d_in[13];
    float* out = (float*)d_out;

    const int M = 8192;
    uint8_t* ws = (uint8_t*)d_ws;
    f16* wT_qkv = (f16*)(ws + 0);                 //  6 MB [3072,1024]
    f16* wT_o   = (f16*)(ws + 6291456);           //  2 MB [1024,1024]
    f16* wT_i   = (f16*)(ws + 8388608);           //  8 MB [4096,1024]
    f16* wT_out = (f16*)(ws + 16777216);          //  8 MB [1024,4096]
    f16* xln    = (f16*)(ws + 25165824);          // 16 MB [8192,1024]
    float* x1   = (float*)(ws + 41943040);        // 32 MB fp32 [8192,1024]
    f16* qbuf   = (f16*)(ws + 75497472);          // 16 MB [b,h,s,d]
    f16* kbuf   = (f16*)(ws + 92274688);          // 16 MB [b,h,s,d]
    f16* vbuf   = (f16*)(ws + 109051904);         // 16 MB [b,h,d,s]
    f16* ctx    = (f16*)(ws + 125829120);         // 16 MB [8192,1024]
    f16* hbuf   = (f16*)(ws + 75497472);          // 64 MB [8192,4096] (aliases q/k/v/ctx, dead by then)

    transpose_f16_kernel<<<dim3(96, 32),  256, 0, stream>>>(qkvw, wT_qkv, 1024, 3072);
    transpose_f16_kernel<<<dim3(32, 32),  256, 0, stream>>>(ow,   wT_o,   1024, 1024);
    transpose_f16_kernel<<<dim3(128, 32), 256, 0, stream>>>(iw,   wT_i,   1024, 4096);
    transpose_f16_kernel<<<dim3(32, 128), 256, 0, stream>>>(outw, wT_out, 4096, 1024);

    ln_f16_kernel<<<8192, 256, 0, stream>>>(inputs, anw, anb, xln);

    gemm_big_kernel<2><<<dim3(32, 24), 256, 0, stream>>>(xln, wT_qkv, qkvb,
        nullptr, qbuf, kbuf, vbuf, M, 3072, 1024);

    attn_kernel<<<dim3(16, 16, 8), 256, 0, stream>>>(qbuf, kbuf, vbuf, mask, ctx);

    gemm_kernel<<<dim3(64, 8), 256, 0, stream>>>(ctx, wT_o, ob, inputs,
        x1, M, 1024, 1024);

    ln_f16_kernel<<<8192, 256, 0, stream>>>(x1, fnw, fnb, xln);

    gemm_big_kernel<1><<<dim3(32, 32), 256, 0, stream>>>(xln, wT_i, ib,
        hbuf, nullptr, nullptr, nullptr, M, 4096, 1024);

    gemm_kernel<<<dim3(64, 8), 256, 0, stream>>>(hbuf, wT_out, outb, x1,
        out, M, 1024, 4096);
}